// Round 6
// baseline (542.169 us; speedup 1.0000x reference)
//
#include <hip/hip_runtime.h>
#include <hip/hip_bf16.h>
#include <hip/hip_cooperative_groups.h>
#include <math.h>

namespace cg = cooperative_groups;

#define NB 4
#define NL 2048
#define NH 8
#define NE 64
#define ND 64
#define EPSF 1e-6f
#define CEXP 0.180336881f  // 0.125 * log2(e); scores L2-bounded in [-1,1] => fixed max 1.0

typedef __attribute__((ext_vector_type(8))) short bf16x8;
typedef __attribute__((ext_vector_type(4))) short s16x4;
typedef __attribute__((ext_vector_type(4))) float f32x4;

static __device__ __forceinline__ unsigned short bfbits(float x) {
  union { __hip_bfloat16 h; unsigned short u; } c;
  c.h = __float2bfloat16(x);
  return c.u;
}
static __device__ __forceinline__ float sgnsqrt(float x) {
  return x > 0.f ? sqrtf(x + EPSF) : (x < 0.f ? -sqrtf(-x + EPSF) : 0.f);
}

// ---------------- cooperative fused prep -----------------------------------------
// 1024 blocks x 256 thr, all co-resident (4 blocks/CU).
// Phase 1: load 64-row q/k slab into REGISTERS (32+32 f32/thread), emit per-slab
//          partial sums; also one vtrans tile per block.  grid.sync()
// Phase 2a: 32 blocks reduce 256 slab-partials -> total q/k sums.  grid.sync()
// Phase 2b: adjust from register slabs (no re-read), write bf16 qadj/kadj.
__global__ __launch_bounds__(256, 4) void prep_kernel(
    const float* __restrict__ q, const float* __restrict__ k, const float* __restrict__ v,
    const float* __restrict__ alpha,
    float* __restrict__ pq, float* __restrict__ pk,
    float* __restrict__ qsumT, float* __restrict__ ksumT,
    __hip_bfloat16* __restrict__ qadj, __hip_bfloat16* __restrict__ kadj,
    __hip_bfloat16* __restrict__ vt) {
  __shared__ __align__(16) char sh[16384];
  cg::grid_group grid = cg::this_grid();
  int blk = blockIdx.x;       // 0..1023
  int t = threadIdx.x;
  int b = blk >> 8;           // 256 blocks per b
  int col4 = t & 15;          // f32x4 column group within row

  // ---- phase 1: register slab load (rows rid0..rid0+63; thread j-th row = (t>>4)+16j)
  int rid0 = blk * 64;
  f32x4 q4[4], k4[4];
#pragma unroll
  for (int j = 0; j < 4; ++j) {
    size_t off = ((size_t)(rid0 + (t >> 4) + 16 * j) * 64 + col4 * 4);
    q4[j] = *(const f32x4*)(q + off);
    k4[j] = *(const f32x4*)(k + off);
  }
  // per-thread partial over its 4 rows (all same h = (t>>4)&7)
  {
    f32x4* arr = (f32x4*)sh;
    f32x4 ps = (q4[0] + q4[1]) + (q4[2] + q4[3]);
    arr[t] = ps;
    __syncthreads();
    if (t < 128) {
      f32x4 tot = arr[t] + arr[t + 128];
      int h = (t >> 4) & 7;
      *(f32x4*)(pq + (size_t)blk * 512 + h * 64 + col4 * 4) = tot;
    }
    __syncthreads();
    ps = (k4[0] + k4[1]) + (k4[2] + k4[3]);
    arr[t] = ps;
    __syncthreads();
    if (t < 128) {
      f32x4 tot = arr[t] + arr[t + 128];
      int h = (t >> 4) & 7;
      *(f32x4*)(pk + (size_t)blk * 512 + h * 64 + col4 * 4) = tot;
    }
    __syncthreads();
  }
  // ---- vtrans job (1 per block): V [B,S,H,D] f32 -> VT [B,H,D,Sperm] bf16
  {
    __hip_bfloat16 (*tile)[68] = (__hip_bfloat16(*)[68])(sh + 4096);
    int vbh = blk >> 5, s0 = (blk & 31) * 64;
    int vb = vbh >> 3, vh = vbh & 7;
    int sl = t >> 2, dg = t & 3;
    const float* src = v + (((size_t)vb * NL + s0 + sl) * NH + vh) * ND + dg * 16;
#pragma unroll
    for (int i = 0; i < 4; ++i) {
      f32x4 f = *(const f32x4*)(src + i * 4);
      tile[sl][dg * 16 + i * 4 + 0] = __float2bfloat16(f[0]);
      tile[sl][dg * 16 + i * 4 + 1] = __float2bfloat16(f[1]);
      tile[sl][dg * 16 + i * 4 + 2] = __float2bfloat16(f[2]);
      tile[sl][dg * 16 + i * 4 + 3] = __float2bfloat16(f[3]);
    }
    __syncthreads();
    int d = t >> 2, sg = t & 3;
    __align__(16) __hip_bfloat16 tmp[16];
#pragma unroll
    for (int i = 0; i < 16; ++i) {
      int c = sg * 16 + i;
      int blk32 = c >> 5, cc = c & 31;
      int cq = cc >> 2, ege = cq >> 1, hi = cq & 1;
      int s_local = blk32 * 32 + hi * 16 + ege * 4 + (cc & 3);
      tmp[i] = tile[s_local][d];
    }
    __hip_bfloat16* dst = vt + ((size_t)vbh * ND + d) * NL + s0 + sg * 16;
    *(bf16x8*)(dst) = *(const bf16x8*)&tmp[0];
    *(bf16x8*)(dst + 8) = *(const bf16x8*)&tmp[8];
  }

  __threadfence();
  grid.sync();

  // ---- phase 2a: 32 blocks (one per bh) reduce 256 slab-partials ----
  if (blk < 32) {
    int rb = blk >> 3, rh = blk & 7;
    int e = t & 63, g = t >> 6;
    float* red = (float*)sh;
    float sq = 0.f, sk = 0.f;
    for (int i = 0; i < 64; ++i) {
      size_t sb = (size_t)(rb * 256 + g + 4 * i) * 512 + rh * 64 + e;
      sq += pq[sb];
      sk += pk[sb];
    }
    red[g * 64 + e] = sq;
    red[256 + g * 64 + e] = sk;
    __syncthreads();
    if (t < 64) {
      qsumT[blk * 64 + t] = red[t] + red[64 + t] + red[128 + t] + red[192 + t];
      ksumT[blk * 64 + t] = red[256 + t] + red[320 + t] + red[384 + t] + red[448 + t];
    }
  }

  __threadfence();
  grid.sync();

  // ---- phase 2b: adjust from register slabs, write bf16 ----
  {
    float* tabq = (float*)sh;          // alpha * qsum for this b (8h x 64e)
    float* tabk = (float*)(sh + 2048); // alpha * ksum
    float al = alpha[0];
    if (t < 128) {
      f32x4 a = *(const f32x4*)(qsumT + b * 512 + t * 4);
      f32x4 c = *(const f32x4*)(ksumT + b * 512 + t * 4);
      *(f32x4*)(tabq + t * 4) = a * al;
      *(f32x4*)(tabk + t * 4) = c * al;
    }
    __syncthreads();
    int h = (t >> 4) & 7;
    f32x4 aq = *(const f32x4*)(tabk + h * 64 + col4 * 4);  // q + alpha*k_sum
    f32x4 ak = *(const f32x4*)(tabq + h * 64 + col4 * 4);  // k + alpha*q_sum
    int bh = b * 8 + h;
#pragma unroll
    for (int j = 0; j < 4; ++j) {
      f32x4 xq = q4[j] + aq;
      f32x4 xk = k4[j] + ak;
      float yq[4], yk[4];
      float nq = 0.f, nk = 0.f;
#pragma unroll
      for (int c = 0; c < 4; ++c) {
        yq[c] = sgnsqrt(xq[c]); nq += yq[c] * yq[c];
        yk[c] = sgnsqrt(xk[c]); nk += yk[c] * yk[c];
      }
#pragma unroll
      for (int m = 1; m < 16; m <<= 1) {
        nq += __shfl_xor(nq, m, 16);
        nk += __shfl_xor(nk, m, 16);
      }
      float iq = 1.f / (sqrtf(nq) + EPSF);
      float ik = 1.f / (sqrtf(nk) + EPSF);
      s16x4 uq, uk;
#pragma unroll
      for (int c = 0; c < 4; ++c) {
        uq[c] = (short)bfbits(yq[c] * iq);
        uk[c] = (short)bfbits(yk[c] * ik);
      }
      int l = (blk & 255) * 8 + (t >> 7) + 2 * j;
      size_t ooff = ((size_t)bh * 2048 + l) * 64 + col4 * 4;
      *(s16x4*)((char*)qadj + ooff * 2) = uq;
      *(s16x4*)((char*)kadj + ooff * 2) = uk;
    }
  }
}

// ---------------- causal flash attention -----------------------------------------
// 256 thr = 4 waves: wave = (qhalf, shalf). 32 q-rows/block, one tile/block,
// 64-s chunks; wave computes 16 q x 32 s. Grid 32 bh x 64 tiles (big-first).
// Triple-buffered K/V (3 x 16KB), depth-2 prefetch, counted vmcnt(4) (T4);
// setprio around MFMA clusters (T5). 48KB LDS -> 3 blocks/CU.
__global__ __launch_bounds__(256, 3) void attn_kernel(const __hip_bfloat16* __restrict__ qadj,
                                                      const __hip_bfloat16* __restrict__ kadj,
                                                      const __hip_bfloat16* __restrict__ vt,
                                                      float* __restrict__ out) {
  __shared__ __align__(16) char lds[49152];
  int bh = blockIdx.x;              // fastest => same-bh blocks cluster on an XCD
  int tile = 63 - (int)blockIdx.y;  // big tiles dispatch first
  int b = bh >> 3, h = bh & 7;
  int wave = threadIdx.x >> 6, lane = threadIdx.x & 63;
  int qr = lane & 15, eg = lane >> 4;
  int qhalf = wave >> 1, shalf = wave & 1;
  int t0 = tile * 32;
  int nck = (tile >> 1) + 1;
  int qw0 = t0 + qhalf * 16;
  const char* kgb = (const char*)(kadj + (size_t)bh * NL * NE);
  const char* vgb = (const char*)(vt + (size_t)bh * ND * NL);
  const char* qgb = (const char*)(qadj + (size_t)bh * NL * NE);

  // ---- hoisted LDS fragment offsets ----
  int koff[2][2], voff[4];
#pragma unroll
  for (int st2 = 0; st2 < 2; ++st2) {
    int row = shalf * 32 + st2 * 16 + qr;
    int swz = (row & 7) << 4;
    koff[st2][0] = (row * 128 + eg * 16) ^ swz;
    koff[st2][1] = (row * 128 + 64 + eg * 16) ^ swz;
  }
#pragma unroll
  for (int dc = 0; dc < 4; ++dc) {
    int d = dc * 16 + qr;
    voff[dc] = 8192 + ((d * 128 + shalf * 64 + eg * 16) ^ ((d & 7) << 4));
  }
  // ---- hoisted staging offsets: waves 0-1 stage K, waves 2-3 stage V ----
  int src_off[4], dst_off[4];
#pragma unroll
  for (int c = 0; c < 4; ++c) {
    dst_off[c] = (wave * 4 + c) * 1024;
    if (wave < 2) {
      int T = (wave * 4 + c) * 1024 + lane * 16;
      src_off[c] = T ^ (((T >> 7) & 7) << 4);
    } else {
      int T2 = ((wave - 2) * 4 + c) * 1024 + lane * 16;
      int S = T2 ^ (((T2 >> 7) & 7) << 4);
      src_off[c] = (S >> 7) * (NL * 2) + (S & 127);
    }
  }
  const char* sgb = (wave < 2) ? kgb : vgb;
  int smul = (wave < 2) ? 8192 : 128;  // global bytes per 64-s chunk step

  auto STAGE = [&](int bufoff, int ck) {
    const char* sb = sgb + (size_t)ck * smul;
    char* db = lds + bufoff;
#pragma unroll
    for (int c = 0; c < 4; ++c)
      __builtin_amdgcn_global_load_lds(
          (const __attribute__((address_space(1))) unsigned int*)(sb + src_off[c]),
          (__attribute__((address_space(3))) unsigned int*)(db + dst_off[c]),
          16, 0, 0);
  };

  bf16x8 qf0 = *(const bf16x8*)(qgb + (size_t)(qw0 + qr) * 128 + eg * 16);
  bf16x8 qf1 = *(const bf16x8*)(qgb + (size_t)(qw0 + qr) * 128 + 64 + eg * 16);

  f32x4 acc[4];
#pragma unroll
  for (int dc = 0; dc < 4; ++dc) acc[dc] = (f32x4){0.f, 0.f, 0.f, 0.f};
  float srun = 0.f;

  // prologue: depth-2 prefetch
  STAGE(0, 0);
  if (nck > 1) STAGE(16384, 1);

  int off_c = 0;        // compute buffer byte offset
  int off_s = 32768;    // stage target = 2 ahead
#pragma unroll 1
  for (int ck = 0; ck < nck; ++ck) {
    if (ck + 1 < nck) asm volatile("s_waitcnt vmcnt(4)" ::: "memory");
    else              asm volatile("s_waitcnt vmcnt(0)" ::: "memory");
    __builtin_amdgcn_sched_barrier(0);
    __builtin_amdgcn_s_barrier();
    __builtin_amdgcn_sched_barrier(0);
    if (ck + 2 < nck) STAGE(off_s, ck + 2);
    char* base = lds + off_c;

    // ---- swapped QK^T: p[st2][r] = P[s][q], s = ck*64+shalf*32+st2*16+eg*4+r ----
    float p[2][4];
    __builtin_amdgcn_s_setprio(1);
#pragma unroll
    for (int st2 = 0; st2 < 2; ++st2) {
      f32x4 a = (f32x4){0.f, 0.f, 0.f, 0.f};
      bf16x8 k0 = *(const bf16x8*)(base + koff[st2][0]);
      bf16x8 k1 = *(const bf16x8*)(base + koff[st2][1]);
      a = __builtin_amdgcn_mfma_f32_16x16x32_bf16(k0, qf0, a, 0, 0, 0);
      a = __builtin_amdgcn_mfma_f32_16x16x32_bf16(k1, qf1, a, 0, 0, 0);
#pragma unroll
      for (int r = 0; r < 4; ++r) p[st2][r] = a[r];
    }
    __builtin_amdgcn_s_setprio(0);
    if (ck == nck - 1) {  // diagonal chunk: strict causal mask s > q
      int sbase = ck * 64 + shalf * 32 + eg * 4;
      int qg = qw0 + qr;
#pragma unroll
      for (int st2 = 0; st2 < 2; ++st2)
#pragma unroll
        for (int r = 0; r < 4; ++r)
          if (sbase + st2 * 16 + r > qg) p[st2][r] = -1e30f;
    }
    // ---- fixed-max softmax numerators; per-lane partial denominator ----
#pragma unroll
    for (int st2 = 0; st2 < 2; ++st2)
#pragma unroll
      for (int r = 0; r < 4; ++r) p[st2][r] = exp2f((p[st2][r] - 1.0f) * CEXP);
    srun += ((p[0][0] + p[0][1]) + (p[0][2] + p[0][3])) +
            ((p[1][0] + p[1][1]) + (p[1][2] + p[1][3]));

    // ---- PV: O^T = V^T * P, B-fragment direct from registers ----
    bf16x8 pb;
#pragma unroll
    for (int j = 0; j < 4; ++j) {
      pb[j] = (short)bfbits(p[0][j]);
      pb[4 + j] = (short)bfbits(p[1][j]);
    }
    __builtin_amdgcn_s_setprio(1);
#pragma unroll
    for (int dc = 0; dc < 4; ++dc) {
      bf16x8 vf = *(const bf16x8*)(base + voff[dc]);
      acc[dc] = __builtin_amdgcn_mfma_f32_16x16x32_bf16(vf, pb, acc[dc], 0, 0, 0);
    }
    __builtin_amdgcn_s_setprio(0);

    off_c = (off_c == 32768) ? 0 : off_c + 16384;
    off_s = (off_s == 32768) ? 0 : off_s + 16384;
  }

  // ---- epilogue: reduce srun over eg, merge s-halves via LDS, store ----
  srun += __shfl_xor(srun, 16, 64);
  srun += __shfl_xor(srun, 32, 64);
  __syncthreads();  // all K/V reads complete; buffers reusable as merge area
  if (shalf == 1) {
    float* m = (float*)(lds + qhalf * 4352 + lane * 68);
#pragma unroll
    for (int dc = 0; dc < 4; ++dc)
#pragma unroll
      for (int r = 0; r < 4; ++r) m[dc * 4 + r] = acc[dc][r];
    m[16] = srun;
  }
  __syncthreads();
  if (shalf == 0) {
    const float* m = (const float*)(lds + qhalf * 4352 + lane * 68);
#pragma unroll
    for (int dc = 0; dc < 4; ++dc)
#pragma unroll
      for (int r = 0; r < 4; ++r) acc[dc][r] += m[dc * 4 + r];
    float inv = 1.f / (srun + m[16]);
    int l = qw0 + qr;
    float* orow = out + (((size_t)b * NL + l) * NH + h) * ND;
#pragma unroll
    for (int dc = 0; dc < 4; ++dc) *(f32x4*)(orow + dc * 16 + eg * 4) = acc[dc] * inv;
  }
}

extern "C" void kernel_launch(void* const* d_in, const int* in_sizes, int n_in,
                              void* d_out, int out_size, void* d_ws, size_t ws_size,
                              hipStream_t stream) {
  const float* q = (const float*)d_in[0];
  const float* k = (const float*)d_in[1];
  const float* v = (const float*)d_in[2];
  // d_in[3] = attn_mask: deterministic triu(k=1) causal mask — applied analytically
  const float* alpha = (const float*)d_in[4];
  float* out = (float*)d_out;
  char* ws = (char*)d_ws;

  __hip_bfloat16* qadj = (__hip_bfloat16*)(ws);                 // 8 MiB [B,H,L,E]
  __hip_bfloat16* kadj = (__hip_bfloat16*)(ws + 8388608);       // 8 MiB [B,H,L,E]
  __hip_bfloat16* vt   = (__hip_bfloat16*)(ws + 16777216);      // 8 MiB [B,H,D,Sperm]
  float* pq    = (float*)(ws + 25165824);                       // 2 MiB slab partials
  float* pk    = (float*)(ws + 25165824 + 2097152);             // 2 MiB
  float* qsumT = (float*)(ws + 25165824 + 4194304);             // 8 KiB totals
  float* ksumT = (float*)(ws + 25165824 + 4194304 + 8192);      // 8 KiB

  void* args[] = {(void*)&q, (void*)&k, (void*)&v, (void*)&alpha,
                  (void*)&pq, (void*)&pk, (void*)&qsumT, (void*)&ksumT,
                  (void*)&qadj, (void*)&kadj, (void*)&vt};
  hipLaunchCooperativeKernel((const void*)prep_kernel, dim3(1024), dim3(256),
                             args, 0, stream);
  attn_kernel<<<dim3(32, 64), 256, 0, stream>>>(qadj, kadj, vt, out);
}

// Round 7
// 160.892 us; speedup vs baseline: 3.3698x; 3.3698x over previous
//
#include <hip/hip_runtime.h>
#include <hip/hip_bf16.h>
#include <math.h>

#define NB 4
#define NL 2048
#define NH 8
#define NE 64
#define ND 64
#define EPSF 1e-6f
#define CEXP 0.180336881f  // 0.125 * log2(e); scores L2-bounded in [-1,1] => fixed max 1.0

typedef __attribute__((ext_vector_type(8))) short bf16x8;
typedef __attribute__((ext_vector_type(4))) short s16x4;
typedef __attribute__((ext_vector_type(4))) float f32x4;

static __device__ __forceinline__ unsigned short bfbits(float x) {
  union { __hip_bfloat16 h; unsigned short u; } c;
  c.h = __float2bfloat16(x);
  return c.u;
}
static __device__ __forceinline__ float b2f(short s) {
  union { float f; unsigned u; } c;
  c.u = ((unsigned)(unsigned short)s) << 16;
  return c.f;
}
static __device__ __forceinline__ float sgnsqrt(float x) {
  return x > 0.f ? sqrtf(x + EPSF) : (x < 0.f ? -sqrtf(-x + EPSF) : 0.f);
}

// ---- kernel A: stream q/k once: slab partial sums + bf16 copies in [B,H,L,E] ----
// 1024 blocks x 256 thr; block = 64 consecutive (l,h) rows. Fully coalesced.
__global__ __launch_bounds__(256) void sums_kernel(
    const float* __restrict__ q, const float* __restrict__ k,
    float* __restrict__ pq, float* __restrict__ pk,
    __hip_bfloat16* __restrict__ qbf, __hip_bfloat16* __restrict__ kbf) {
  __shared__ f32x4 arr[256];
  int blk = blockIdx.x, t = threadIdx.x;
  int col4 = t & 15;
  int rid0 = blk * 64;
  f32x4 q4[4], k4[4];
#pragma unroll
  for (int j = 0; j < 4; ++j) {
    size_t off = ((size_t)(rid0 + (t >> 4) + 16 * j) * 64 + col4 * 4);
    q4[j] = *(const f32x4*)(q + off);
    k4[j] = *(const f32x4*)(k + off);
  }
  // per-(h,e) partial sums: thread's 4 rows share h = (t>>4)&7
  arr[t] = (q4[0] + q4[1]) + (q4[2] + q4[3]);
  __syncthreads();
  if (t < 128) *(f32x4*)(pq + (size_t)blk * 512 + (t >> 4) * 64 + col4 * 4) = arr[t] + arr[t + 128];
  __syncthreads();
  arr[t] = (k4[0] + k4[1]) + (k4[2] + k4[3]);
  __syncthreads();
  if (t < 128) *(f32x4*)(pk + (size_t)blk * 512 + (t >> 4) * 64 + col4 * 4) = arr[t] + arr[t + 128];
  // bf16 copies, transposed to [B,H,L,E] (rows stay contiguous; only row order maps)
#pragma unroll
  for (int j = 0; j < 4; ++j) {
    int rid = rid0 + (t >> 4) + 16 * j;
    int bb = rid >> 14, l = (rid >> 3) & 2047, h = rid & 7;
    size_t o = ((size_t)(bb * 8 + h) * 2048 + l) * 64 + col4 * 4;
    s16x4 uq, uk;
#pragma unroll
    for (int c = 0; c < 4; ++c) {
      uq[c] = (short)bfbits(q4[j][c]);
      uk[c] = (short)bfbits(k4[j][c]);
    }
    *(s16x4*)((char*)qbf + o * 2) = uq;
    *(s16x4*)((char*)kbf + o * 2) = uk;
  }
}

// ---- kernel B: fold 256 slab-partials per b -> exact f32 sums per (bh,e) ----
__global__ __launch_bounds__(256) void reduce_kernel(
    const float* __restrict__ pq, const float* __restrict__ pk,
    float* __restrict__ qsumT, float* __restrict__ ksumT) {
  __shared__ float red[512];
  int bh = blockIdx.x;
  int rb = bh >> 3, rh = bh & 7;
  int t = threadIdx.x, e = t & 63, g = t >> 6;
  float sq = 0.f, sk = 0.f;
#pragma unroll 4
  for (int i = 0; i < 64; ++i) {
    size_t sb = (size_t)(rb * 256 + g + 4 * i) * 512 + rh * 64 + e;
    sq += pq[sb];
    sk += pk[sb];
  }
  red[g * 64 + e] = sq;
  __syncthreads();
  if (t < 64) qsumT[bh * 64 + t] = red[t] + red[64 + t] + red[128 + t] + red[192 + t];
  __syncthreads();
  red[g * 64 + e] = sk;
  __syncthreads();
  if (t < 64) ksumT[bh * 64 + t] = red[t] + red[64 + t] + red[128 + t] + red[192 + t];
}

// ---- kernel C: adjust from bf16 copies (blocks 0..1023) + vtrans (1024..2047) ----
__global__ __launch_bounds__(256) void prep_kernel(
    const __hip_bfloat16* __restrict__ qbf, const __hip_bfloat16* __restrict__ kbf,
    const float* __restrict__ v,
    const float* __restrict__ qsumT, const float* __restrict__ ksumT,
    const float* __restrict__ alpha,
    __hip_bfloat16* __restrict__ qadj, __hip_bfloat16* __restrict__ kadj,
    __hip_bfloat16* __restrict__ vt) {
  __shared__ __align__(16) char sh[9216];
  int t = threadIdx.x;
  if (blockIdx.x < 1024) {
    // ---- adjust: 64 rows of one bh; 8 threads/row, bf16x8 per thread ----
    int bh = blockIdx.x >> 5, l0 = (blockIdx.x & 31) * 64;
    float* aq = (float*)sh;          // alpha * q_sum for this bh
    float* ak = (float*)(sh + 256);  // alpha * k_sum
    if (t < 64) {
      float al = alpha[0];
      aq[t] = al * qsumT[bh * 64 + t];
      ak[t] = al * ksumT[bh * 64 + t];
    }
    __syncthreads();
    int e8 = t & 7, rr = t >> 3;
#pragma unroll
    for (int p = 0; p < 2; ++p) {
      int l = l0 + p * 32 + rr;
      size_t o = ((size_t)bh * 2048 + l) * 64 + e8 * 8;
      bf16x8 xq8 = *(const bf16x8*)((const char*)qbf + o * 2);
      bf16x8 xk8 = *(const bf16x8*)((const char*)kbf + o * 2);
      float yq[8], yk[8];
      float nq = 0.f, nk = 0.f;
#pragma unroll
      for (int c = 0; c < 8; ++c) {
        float xq = b2f(xq8[c]) + ak[e8 * 8 + c];  // q + alpha*k_sum
        float xk = b2f(xk8[c]) + aq[e8 * 8 + c];  // k + alpha*q_sum
        yq[c] = sgnsqrt(xq); nq += yq[c] * yq[c];
        yk[c] = sgnsqrt(xk); nk += yk[c] * yk[c];
      }
#pragma unroll
      for (int m = 1; m < 8; m <<= 1) {
        nq += __shfl_xor(nq, m, 8);
        nk += __shfl_xor(nk, m, 8);
      }
      float iq = 1.f / (sqrtf(nq) + EPSF);
      float ik = 1.f / (sqrtf(nk) + EPSF);
      bf16x8 uq, uk;
#pragma unroll
      for (int c = 0; c < 8; ++c) {
        uq[c] = (short)bfbits(yq[c] * iq);
        uk[c] = (short)bfbits(yk[c] * ik);
      }
      *(bf16x8*)((char*)qadj + o * 2) = uq;
      *(bf16x8*)((char*)kadj + o * 2) = uk;
    }
  } else {
    // ---- vtrans: V [B,S,H,D] f32 -> VT [B,H,D,Sperm] bf16, quad-interleaved cols ----
    __hip_bfloat16 (*tile)[68] = (__hip_bfloat16(*)[68])sh;
    int blk = blockIdx.x - 1024;
    int s0 = (blk & 31) * 64;
    int bh = blk >> 5;
    int b = bh >> 3, h = bh & 7;
    {
      int sl = t >> 2, dg = t & 3;
      const float* src = v + (((size_t)b * NL + s0 + sl) * NH + h) * ND + dg * 16;
#pragma unroll
      for (int i = 0; i < 4; ++i) {
        f32x4 f = *(const f32x4*)(src + i * 4);
        tile[sl][dg * 16 + i * 4 + 0] = __float2bfloat16(f[0]);
        tile[sl][dg * 16 + i * 4 + 1] = __float2bfloat16(f[1]);
        tile[sl][dg * 16 + i * 4 + 2] = __float2bfloat16(f[2]);
        tile[sl][dg * 16 + i * 4 + 3] = __float2bfloat16(f[3]);
      }
    }
    __syncthreads();
    {
      int d = t >> 2, sg = t & 3;
      __align__(16) __hip_bfloat16 tmp[16];
#pragma unroll
      for (int i = 0; i < 16; ++i) {
        int c = sg * 16 + i;
        int blk32 = c >> 5, cc = c & 31;
        int cq = cc >> 2, ege = cq >> 1, hi = cq & 1;
        int s_local = blk32 * 32 + hi * 16 + ege * 4 + (cc & 3);
        tmp[i] = tile[s_local][d];
      }
      __hip_bfloat16* dst = vt + ((size_t)bh * ND + d) * NL + s0 + sg * 16;
      *(bf16x8*)(dst) = *(const bf16x8*)&tmp[0];
      *(bf16x8*)(dst + 8) = *(const bf16x8*)&tmp[8];
    }
  }
}

// ---------------- causal flash attention (UNCHANGED from R5/R6 — validated) ------
// 256 thr = 4 waves: wave = (qhalf, shalf). 32 q-rows/block, one tile/block,
// 64-s chunks; wave computes 16 q x 32 s. Grid 32 bh x 64 tiles (big-first).
// Triple-buffered K/V (3 x 16KB), depth-2 prefetch, counted vmcnt(4) (T4);
// setprio around MFMA clusters (T5). 48KB LDS -> 3 blocks/CU.
__global__ __launch_bounds__(256, 3) void attn_kernel(const __hip_bfloat16* __restrict__ qadj,
                                                      const __hip_bfloat16* __restrict__ kadj,
                                                      const __hip_bfloat16* __restrict__ vt,
                                                      float* __restrict__ out) {
  __shared__ __align__(16) char lds[49152];
  int bh = blockIdx.x;              // fastest => same-bh blocks cluster on an XCD
  int tile = 63 - (int)blockIdx.y;  // big tiles dispatch first
  int b = bh >> 3, h = bh & 7;
  int wave = threadIdx.x >> 6, lane = threadIdx.x & 63;
  int qr = lane & 15, eg = lane >> 4;
  int qhalf = wave >> 1, shalf = wave & 1;
  int t0 = tile * 32;
  int nck = (tile >> 1) + 1;
  int qw0 = t0 + qhalf * 16;
  const char* kgb = (const char*)(kadj + (size_t)bh * NL * NE);
  const char* vgb = (const char*)(vt + (size_t)bh * ND * NL);
  const char* qgb = (const char*)(qadj + (size_t)bh * NL * NE);

  // ---- hoisted LDS fragment offsets ----
  int koff[2][2], voff[4];
#pragma unroll
  for (int st2 = 0; st2 < 2; ++st2) {
    int row = shalf * 32 + st2 * 16 + qr;
    int swz = (row & 7) << 4;
    koff[st2][0] = (row * 128 + eg * 16) ^ swz;
    koff[st2][1] = (row * 128 + 64 + eg * 16) ^ swz;
  }
#pragma unroll
  for (int dc = 0; dc < 4; ++dc) {
    int d = dc * 16 + qr;
    voff[dc] = 8192 + ((d * 128 + shalf * 64 + eg * 16) ^ ((d & 7) << 4));
  }
  // ---- hoisted staging offsets: waves 0-1 stage K, waves 2-3 stage V ----
  int src_off[4], dst_off[4];
#pragma unroll
  for (int c = 0; c < 4; ++c) {
    dst_off[c] = (wave * 4 + c) * 1024;
    if (wave < 2) {
      int T = (wave * 4 + c) * 1024 + lane * 16;
      src_off[c] = T ^ (((T >> 7) & 7) << 4);
    } else {
      int T2 = ((wave - 2) * 4 + c) * 1024 + lane * 16;
      int S = T2 ^ (((T2 >> 7) & 7) << 4);
      src_off[c] = (S >> 7) * (NL * 2) + (S & 127);
    }
  }
  const char* sgb = (wave < 2) ? kgb : vgb;
  int smul = (wave < 2) ? 8192 : 128;  // global bytes per 64-s chunk step

  auto STAGE = [&](int bufoff, int ck) {
    const char* sb = sgb + (size_t)ck * smul;
    char* db = lds + bufoff;
#pragma unroll
    for (int c = 0; c < 4; ++c)
      __builtin_amdgcn_global_load_lds(
          (const __attribute__((address_space(1))) unsigned int*)(sb + src_off[c]),
          (__attribute__((address_space(3))) unsigned int*)(db + dst_off[c]),
          16, 0, 0);
  };

  bf16x8 qf0 = *(const bf16x8*)(qgb + (size_t)(qw0 + qr) * 128 + eg * 16);
  bf16x8 qf1 = *(const bf16x8*)(qgb + (size_t)(qw0 + qr) * 128 + 64 + eg * 16);

  f32x4 acc[4];
#pragma unroll
  for (int dc = 0; dc < 4; ++dc) acc[dc] = (f32x4){0.f, 0.f, 0.f, 0.f};
  float srun = 0.f;

  // prologue: depth-2 prefetch
  STAGE(0, 0);
  if (nck > 1) STAGE(16384, 1);

  int off_c = 0;        // compute buffer byte offset
  int off_s = 32768;    // stage target = 2 ahead
#pragma unroll 1
  for (int ck = 0; ck < nck; ++ck) {
    if (ck + 1 < nck) asm volatile("s_waitcnt vmcnt(4)" ::: "memory");
    else              asm volatile("s_waitcnt vmcnt(0)" ::: "memory");
    __builtin_amdgcn_sched_barrier(0);
    __builtin_amdgcn_s_barrier();
    __builtin_amdgcn_sched_barrier(0);
    if (ck + 2 < nck) STAGE(off_s, ck + 2);
    char* base = lds + off_c;

    // ---- swapped QK^T: p[st2][r] = P[s][q], s = ck*64+shalf*32+st2*16+eg*4+r ----
    float p[2][4];
    __builtin_amdgcn_s_setprio(1);
#pragma unroll
    for (int st2 = 0; st2 < 2; ++st2) {
      f32x4 a = (f32x4){0.f, 0.f, 0.f, 0.f};
      bf16x8 k0 = *(const bf16x8*)(base + koff[st2][0]);
      bf16x8 k1 = *(const bf16x8*)(base + koff[st2][1]);
      a = __builtin_amdgcn_mfma_f32_16x16x32_bf16(k0, qf0, a, 0, 0, 0);
      a = __builtin_amdgcn_mfma_f32_16x16x32_bf16(k1, qf1, a, 0, 0, 0);
#pragma unroll
      for (int r = 0; r < 4; ++r) p[st2][r] = a[r];
    }
    __builtin_amdgcn_s_setprio(0);
    if (ck == nck - 1) {  // diagonal chunk: strict causal mask s > q
      int sbase = ck * 64 + shalf * 32 + eg * 4;
      int qg = qw0 + qr;
#pragma unroll
      for (int st2 = 0; st2 < 2; ++st2)
#pragma unroll
        for (int r = 0; r < 4; ++r)
          if (sbase + st2 * 16 + r > qg) p[st2][r] = -1e30f;
    }
    // ---- fixed-max softmax numerators; per-lane partial denominator ----
#pragma unroll
    for (int st2 = 0; st2 < 2; ++st2)
#pragma unroll
      for (int r = 0; r < 4; ++r) p[st2][r] = exp2f((p[st2][r] - 1.0f) * CEXP);
    srun += ((p[0][0] + p[0][1]) + (p[0][2] + p[0][3])) +
            ((p[1][0] + p[1][1]) + (p[1][2] + p[1][3]));

    // ---- PV: O^T = V^T * P, B-fragment direct from registers ----
    bf16x8 pb;
#pragma unroll
    for (int j = 0; j < 4; ++j) {
      pb[j] = (short)bfbits(p[0][j]);
      pb[4 + j] = (short)bfbits(p[1][j]);
    }
    __builtin_amdgcn_s_setprio(1);
#pragma unroll
    for (int dc = 0; dc < 4; ++dc) {
      bf16x8 vf = *(const bf16x8*)(base + voff[dc]);
      acc[dc] = __builtin_amdgcn_mfma_f32_16x16x32_bf16(vf, pb, acc[dc], 0, 0, 0);
    }
    __builtin_amdgcn_s_setprio(0);

    off_c = (off_c == 32768) ? 0 : off_c + 16384;
    off_s = (off_s == 32768) ? 0 : off_s + 16384;
  }

  // ---- epilogue: reduce srun over eg, merge s-halves via LDS, store ----
  srun += __shfl_xor(srun, 16, 64);
  srun += __shfl_xor(srun, 32, 64);
  __syncthreads();  // all K/V reads complete; buffers reusable as merge area
  if (shalf == 1) {
    float* m = (float*)(lds + qhalf * 4352 + lane * 68);
#pragma unroll
    for (int dc = 0; dc < 4; ++dc)
#pragma unroll
      for (int r = 0; r < 4; ++r) m[dc * 4 + r] = acc[dc][r];
    m[16] = srun;
  }
  __syncthreads();
  if (shalf == 0) {
    const float* m = (const float*)(lds + qhalf * 4352 + lane * 68);
#pragma unroll
    for (int dc = 0; dc < 4; ++dc)
#pragma unroll
      for (int r = 0; r < 4; ++r) acc[dc][r] += m[dc * 4 + r];
    float inv = 1.f / (srun + m[16]);
    int l = qw0 + qr;
    float* orow = out + (((size_t)b * NL + l) * NH + h) * ND;
#pragma unroll
    for (int dc = 0; dc < 4; ++dc) *(f32x4*)(orow + dc * 16 + eg * 4) = acc[dc] * inv;
  }
}

extern "C" void kernel_launch(void* const* d_in, const int* in_sizes, int n_in,
                              void* d_out, int out_size, void* d_ws, size_t ws_size,
                              hipStream_t stream) {
  const float* q = (const float*)d_in[0];
  const float* k = (const float*)d_in[1];
  const float* v = (const float*)d_in[2];
  // d_in[3] = attn_mask: deterministic triu(k=1) causal mask — applied analytically
  const float* alpha = (const float*)d_in[4];
  float* out = (float*)d_out;
  char* ws = (char*)d_ws;

  __hip_bfloat16* qadj = (__hip_bfloat16*)(ws);                 // 8 MiB [B,H,L,E]
  __hip_bfloat16* kadj = (__hip_bfloat16*)(ws + 8388608);       // 8 MiB [B,H,L,E]
  __hip_bfloat16* vt   = (__hip_bfloat16*)(ws + 16777216);      // 8 MiB [B,H,D,Sperm]
  __hip_bfloat16* qbf  = (__hip_bfloat16*)(ws + 25165824);      // 8 MiB raw bf16 [B,H,L,E]
  __hip_bfloat16* kbf  = (__hip_bfloat16*)(ws + 33554432);      // 8 MiB
  float* pq    = (float*)(ws + 41943040);                       // 2 MiB slab partials
  float* pk    = (float*)(ws + 41943040 + 2097152);             // 2 MiB
  float* qsumT = (float*)(ws + 41943040 + 4194304);             // 8 KiB totals
  float* ksumT = (float*)(ws + 41943040 + 4194304 + 8192);      // 8 KiB

  sums_kernel<<<dim3(1024), 256, 0, stream>>>(q, k, pq, pk, qbf, kbf);
  reduce_kernel<<<dim3(32), 256, 0, stream>>>(pq, pk, qsumT, ksumT);
  prep_kernel<<<dim3(2048), 256, 0, stream>>>(qbf, kbf, v, qsumT, ksumT, alpha, qadj, kadj, vt);
  attn_kernel<<<dim3(32, 64), 256, 0, stream>>>(qadj, kadj, vt, out);
}

// Round 8
// 154.919 us; speedup vs baseline: 3.4997x; 1.0386x over previous
//
#include <hip/hip_runtime.h>
#include <hip/hip_bf16.h>
#include <math.h>

#define NB 4
#define NL 2048
#define NH 8
#define NE 64
#define ND 64
#define EPSF 1e-6f
#define CEXP 0.180336881f  // 0.125 * log2(e); scores L2-bounded in [-1,1] => fixed max 1.0

typedef __attribute__((ext_vector_type(8))) short bf16x8;
typedef __attribute__((ext_vector_type(4))) short s16x4;
typedef __attribute__((ext_vector_type(4))) float f32x4;
typedef __attribute__((ext_vector_type(4))) unsigned int u32x4;

static __device__ __forceinline__ unsigned short bfbits(float x) {
  union { __hip_bfloat16 h; unsigned short u; } c;
  c.h = __float2bfloat16(x);
  return c.u;
}
static __device__ __forceinline__ float b2f(short s) {
  union { float f; unsigned u; } c;
  c.u = ((unsigned)(unsigned short)s) << 16;
  return c.f;
}
static __device__ __forceinline__ float sgnsqrt(float x) {
  return x > 0.f ? sqrtf(x + EPSF) : (x < 0.f ? -sqrtf(-x + EPSF) : 0.f);
}
static __device__ __forceinline__ unsigned cvtpk(float lo, float hi) {
  unsigned r;
  asm("v_cvt_pk_bf16_f32 %0, %1, %2" : "=v"(r) : "v"(lo), "v"(hi));
  return r;
}

// ---- kernel A: stream q/k once: slab partial sums + bf16 copies in [B,H,L,E] ----
__global__ __launch_bounds__(256) void sums_kernel(
    const float* __restrict__ q, const float* __restrict__ k,
    float* __restrict__ pq, float* __restrict__ pk,
    __hip_bfloat16* __restrict__ qbf, __hip_bfloat16* __restrict__ kbf) {
  __shared__ f32x4 arr[256];
  int blk = blockIdx.x, t = threadIdx.x;
  int col4 = t & 15;
  int rid0 = blk * 64;
  f32x4 q4[4], k4[4];
#pragma unroll
  for (int j = 0; j < 4; ++j) {
    size_t off = ((size_t)(rid0 + (t >> 4) + 16 * j) * 64 + col4 * 4);
    q4[j] = *(const f32x4*)(q + off);
    k4[j] = *(const f32x4*)(k + off);
  }
  arr[t] = (q4[0] + q4[1]) + (q4[2] + q4[3]);
  __syncthreads();
  if (t < 128) *(f32x4*)(pq + (size_t)blk * 512 + (t >> 4) * 64 + col4 * 4) = arr[t] + arr[t + 128];
  __syncthreads();
  arr[t] = (k4[0] + k4[1]) + (k4[2] + k4[3]);
  __syncthreads();
  if (t < 128) *(f32x4*)(pk + (size_t)blk * 512 + (t >> 4) * 64 + col4 * 4) = arr[t] + arr[t + 128];
#pragma unroll
  for (int j = 0; j < 4; ++j) {
    int rid = rid0 + (t >> 4) + 16 * j;
    int bb = rid >> 14, l = (rid >> 3) & 2047, h = rid & 7;
    size_t o = ((size_t)(bb * 8 + h) * 2048 + l) * 64 + col4 * 4;
    s16x4 uq, uk;
#pragma unroll
    for (int c = 0; c < 4; ++c) {
      uq[c] = (short)bfbits(q4[j][c]);
      uk[c] = (short)bfbits(k4[j][c]);
    }
    *(s16x4*)((char*)qbf + o * 2) = uq;
    *(s16x4*)((char*)kbf + o * 2) = uk;
  }
}

// ---- kernel B: fold 256 slab-partials per b -> exact f32 sums per (bh,e) ----
__global__ __launch_bounds__(256) void reduce_kernel(
    const float* __restrict__ pq, const float* __restrict__ pk,
    float* __restrict__ qsumT, float* __restrict__ ksumT) {
  __shared__ float red[512];
  int bh = blockIdx.x;
  int rb = bh >> 3, rh = bh & 7;
  int t = threadIdx.x, e = t & 63, g = t >> 6;
  float sq = 0.f, sk = 0.f;
#pragma unroll 4
  for (int i = 0; i < 64; ++i) {
    size_t sb = (size_t)(rb * 256 + g + 4 * i) * 512 + rh * 64 + e;
    sq += pq[sb];
    sk += pk[sb];
  }
  red[g * 64 + e] = sq;
  __syncthreads();
  if (t < 64) qsumT[bh * 64 + t] = red[t] + red[64 + t] + red[128 + t] + red[192 + t];
  __syncthreads();
  red[g * 64 + e] = sk;
  __syncthreads();
  if (t < 64) ksumT[bh * 64 + t] = red[t] + red[64 + t] + red[128 + t] + red[192 + t];
}

// ---- kernel C: adjust from bf16 copies (blocks 0..1023) + vtrans (1024..2047) ----
__global__ __launch_bounds__(256) void prep_kernel(
    const __hip_bfloat16* __restrict__ qbf, const __hip_bfloat16* __restrict__ kbf,
    const float* __restrict__ v,
    const float* __restrict__ qsumT, const float* __restrict__ ksumT,
    const float* __restrict__ alpha,
    __hip_bfloat16* __restrict__ qadj, __hip_bfloat16* __restrict__ kadj,
    __hip_bfloat16* __restrict__ vt) {
  __shared__ __align__(16) char sh[9216];
  int t = threadIdx.x;
  if (blockIdx.x < 1024) {
    int bh = blockIdx.x >> 5, l0 = (blockIdx.x & 31) * 64;
    float* aq = (float*)sh;
    float* ak = (float*)(sh + 256);
    if (t < 64) {
      float al = alpha[0];
      aq[t] = al * qsumT[bh * 64 + t];
      ak[t] = al * ksumT[bh * 64 + t];
    }
    __syncthreads();
    int e8 = t & 7, rr = t >> 3;
#pragma unroll
    for (int p = 0; p < 2; ++p) {
      int l = l0 + p * 32 + rr;
      size_t o = ((size_t)bh * 2048 + l) * 64 + e8 * 8;
      bf16x8 xq8 = *(const bf16x8*)((const char*)qbf + o * 2);
      bf16x8 xk8 = *(const bf16x8*)((const char*)kbf + o * 2);
      float yq[8], yk[8];
      float nq = 0.f, nk = 0.f;
#pragma unroll
      for (int c = 0; c < 8; ++c) {
        float xq = b2f(xq8[c]) + ak[e8 * 8 + c];  // q + alpha*k_sum
        float xk = b2f(xk8[c]) + aq[e8 * 8 + c];  // k + alpha*q_sum
        yq[c] = sgnsqrt(xq); nq += yq[c] * yq[c];
        yk[c] = sgnsqrt(xk); nk += yk[c] * yk[c];
      }
#pragma unroll
      for (int m = 1; m < 8; m <<= 1) {
        nq += __shfl_xor(nq, m, 8);
        nk += __shfl_xor(nk, m, 8);
      }
      float iq = 1.f / (sqrtf(nq) + EPSF);
      float ik = 1.f / (sqrtf(nk) + EPSF);
      bf16x8 uq, uk;
#pragma unroll
      for (int c = 0; c < 8; ++c) {
        uq[c] = (short)bfbits(yq[c] * iq);
        uk[c] = (short)bfbits(yk[c] * ik);
      }
      *(bf16x8*)((char*)qadj + o * 2) = uq;
      *(bf16x8*)((char*)kadj + o * 2) = uk;
    }
  } else {
    __hip_bfloat16 (*tile)[68] = (__hip_bfloat16(*)[68])sh;
    int blk = blockIdx.x - 1024;
    int s0 = (blk & 31) * 64;
    int bh = blk >> 5;
    int b = bh >> 3, h = bh & 7;
    {
      int sl = t >> 2, dg = t & 3;
      const float* src = v + (((size_t)b * NL + s0 + sl) * NH + h) * ND + dg * 16;
#pragma unroll
      for (int i = 0; i < 4; ++i) {
        f32x4 f = *(const f32x4*)(src + i * 4);
        tile[sl][dg * 16 + i * 4 + 0] = __float2bfloat16(f[0]);
        tile[sl][dg * 16 + i * 4 + 1] = __float2bfloat16(f[1]);
        tile[sl][dg * 16 + i * 4 + 2] = __float2bfloat16(f[2]);
        tile[sl][dg * 16 + i * 4 + 3] = __float2bfloat16(f[3]);
      }
    }
    __syncthreads();
    {
      int d = t >> 2, sg = t & 3;
      __align__(16) __hip_bfloat16 tmp[16];
#pragma unroll
      for (int i = 0; i < 16; ++i) {
        int c = sg * 16 + i;
        int blk32 = c >> 5, cc = c & 31;
        int cq = cc >> 2, ege = cq >> 1, hi = cq & 1;
        int s_local = blk32 * 32 + hi * 16 + ege * 4 + (cc & 3);
        tmp[i] = tile[s_local][d];
      }
      __hip_bfloat16* dst = vt + ((size_t)bh * ND + d) * NL + s0 + sg * 16;
      *(bf16x8*)(dst) = *(const bf16x8*)&tmp[0];
      *(bf16x8*)(dst + 8) = *(const bf16x8*)&tmp[8];
    }
  }
}

// ---------------- causal flash attention: 8-wave blocks, cvt_pk pack -------------
// 512 thr = 8 waves: wave = (qg 0..3, shalf 0..1). 64 q-rows/block, one tile/block,
// 64-s chunks; wave computes 16 q x 32 s. Grid 32 bh x 32 tiles (big-first).
// Triple-buffered K/V (3 x 16KB), depth-2 prefetch, counted vmcnt(2), setprio.
// 48KB LDS -> 3 blocks/CU = 24 waves/CU.
__global__ __launch_bounds__(512, 6) void attn_kernel(const __hip_bfloat16* __restrict__ qadj,
                                                      const __hip_bfloat16* __restrict__ kadj,
                                                      const __hip_bfloat16* __restrict__ vt,
                                                      float* __restrict__ out) {
  __shared__ __align__(16) char lds[49152];
  int bh = blockIdx.x;              // fastest => same-bh blocks cluster on an XCD
  int tile = 31 - (int)blockIdx.y;  // big tiles dispatch first
  int b = bh >> 3, h = bh & 7;
  int wave = threadIdx.x >> 6, lane = threadIdx.x & 63;
  int qr = lane & 15, eg = lane >> 4;
  int qg = wave >> 1, shalf = wave & 1;
  int t0 = tile * 64;
  int nck = tile + 1;
  int qw0 = t0 + qg * 16;
  const char* kgb = (const char*)(kadj + (size_t)bh * NL * NE);
  const char* vgb = (const char*)(vt + (size_t)bh * ND * NL);
  const char* qgb = (const char*)(qadj + (size_t)bh * NL * NE);

  // ---- hoisted LDS fragment offsets ----
  int koff[2][2], voff[4];
#pragma unroll
  for (int st2 = 0; st2 < 2; ++st2) {
    int row = shalf * 32 + st2 * 16 + qr;
    int swz = (row & 7) << 4;
    koff[st2][0] = (row * 128 + eg * 16) ^ swz;
    koff[st2][1] = (row * 128 + 64 + eg * 16) ^ swz;
  }
#pragma unroll
  for (int dc = 0; dc < 4; ++dc) {
    int d = dc * 16 + qr;
    voff[dc] = 8192 + ((d * 128 + shalf * 64 + eg * 16) ^ ((d & 7) << 4));
  }
  // ---- staging: waves 0-3 stage K (8KB), waves 4-7 stage V (8KB); 2 loads/wave ----
  int src_off[2], dst_off[2];
#pragma unroll
  for (int c = 0; c < 2; ++c) {
    dst_off[c] = (wave * 2 + c) * 1024;
    if (wave < 4) {
      int T = (wave * 2 + c) * 1024 + lane * 16;
      src_off[c] = T ^ (((T >> 7) & 7) << 4);
    } else {
      int T2 = ((wave - 4) * 2 + c) * 1024 + lane * 16;
      int S = T2 ^ (((T2 >> 7) & 7) << 4);
      src_off[c] = (S >> 7) * (NL * 2) + (S & 127);
    }
  }
  const char* sgb = (wave < 4) ? kgb : vgb;
  int smul = (wave < 4) ? 8192 : 128;  // global bytes per 64-s chunk step

  auto STAGE = [&](int bufoff, int ck) {
    const char* sb = sgb + (size_t)ck * smul;
    char* db = lds + bufoff;
#pragma unroll
    for (int c = 0; c < 2; ++c)
      __builtin_amdgcn_global_load_lds(
          (const __attribute__((address_space(1))) unsigned int*)(sb + src_off[c]),
          (__attribute__((address_space(3))) unsigned int*)(db + dst_off[c]),
          16, 0, 0);
  };

  bf16x8 qf0 = *(const bf16x8*)(qgb + (size_t)(qw0 + qr) * 128 + eg * 16);
  bf16x8 qf1 = *(const bf16x8*)(qgb + (size_t)(qw0 + qr) * 128 + 64 + eg * 16);

  f32x4 acc[4];
#pragma unroll
  for (int dc = 0; dc < 4; ++dc) acc[dc] = (f32x4){0.f, 0.f, 0.f, 0.f};
  float srun = 0.f;

  // prologue: depth-2 prefetch
  STAGE(0, 0);
  if (nck > 1) STAGE(16384, 1);

  int off_c = 0;        // compute buffer byte offset
  int off_s = 32768;    // stage target = 2 ahead
#pragma unroll 1
  for (int ck = 0; ck < nck; ++ck) {
    if (ck + 1 < nck) asm volatile("s_waitcnt vmcnt(2)" ::: "memory");
    else              asm volatile("s_waitcnt vmcnt(0)" ::: "memory");
    __builtin_amdgcn_sched_barrier(0);
    __builtin_amdgcn_s_barrier();
    __builtin_amdgcn_sched_barrier(0);
    if (ck + 2 < nck) STAGE(off_s, ck + 2);
    char* base = lds + off_c;

    // ---- swapped QK^T: s0a[r] = P[s = ck*64+shalf*32+eg*4+r][q = qw0+qr], s1a: +16 ----
    f32x4 s0a = (f32x4){0.f, 0.f, 0.f, 0.f};
    f32x4 s1a = (f32x4){0.f, 0.f, 0.f, 0.f};
    __builtin_amdgcn_s_setprio(1);
    {
      bf16x8 k00 = *(const bf16x8*)(base + koff[0][0]);
      bf16x8 k01 = *(const bf16x8*)(base + koff[0][1]);
      bf16x8 k10 = *(const bf16x8*)(base + koff[1][0]);
      bf16x8 k11 = *(const bf16x8*)(base + koff[1][1]);
      s0a = __builtin_amdgcn_mfma_f32_16x16x32_bf16(k00, qf0, s0a, 0, 0, 0);
      s0a = __builtin_amdgcn_mfma_f32_16x16x32_bf16(k01, qf1, s0a, 0, 0, 0);
      s1a = __builtin_amdgcn_mfma_f32_16x16x32_bf16(k10, qf0, s1a, 0, 0, 0);
      s1a = __builtin_amdgcn_mfma_f32_16x16x32_bf16(k11, qf1, s1a, 0, 0, 0);
    }
    __builtin_amdgcn_s_setprio(0);
    if (ck == nck - 1) {  // diagonal chunk: strict causal mask s > q
      int sbase = ck * 64 + shalf * 32 + eg * 4;
      int qg_ = qw0 + qr;
#pragma unroll
      for (int r = 0; r < 4; ++r) {
        if (sbase + r > qg_) s0a[r] = -1e30f;
        if (sbase + 16 + r > qg_) s1a[r] = -1e30f;
      }
    }
    // ---- fixed-max softmax numerators; per-lane partial denominator ----
#pragma unroll
    for (int r = 0; r < 4; ++r) {
      s0a[r] = exp2f(fmaf(s0a[r], CEXP, -CEXP));
      s1a[r] = exp2f(fmaf(s1a[r], CEXP, -CEXP));
    }
    srun += ((s0a[0] + s0a[1]) + (s0a[2] + s0a[3])) +
            ((s1a[0] + s1a[1]) + (s1a[2] + s1a[3]));

    // ---- pack P -> bf16x8 via v_cvt_pk_bf16_f32 (4 instr instead of ~70) ----
    u32x4 pbw;
    pbw[0] = cvtpk(s0a[0], s0a[1]);
    pbw[1] = cvtpk(s0a[2], s0a[3]);
    pbw[2] = cvtpk(s1a[0], s1a[1]);
    pbw[3] = cvtpk(s1a[2], s1a[3]);
    union { u32x4 u; bf16x8 v; } pbu;
    pbu.u = pbw;

    // ---- PV: O^T = V^T * P, B-fragment direct from registers ----
    __builtin_amdgcn_s_setprio(1);
#pragma unroll
    for (int dc = 0; dc < 4; ++dc) {
      bf16x8 vf = *(const bf16x8*)(base + voff[dc]);
      acc[dc] = __builtin_amdgcn_mfma_f32_16x16x32_bf16(vf, pbu.v, acc[dc], 0, 0, 0);
    }
    __builtin_amdgcn_s_setprio(0);

    off_c = (off_c == 32768) ? 0 : off_c + 16384;
    off_s = (off_s == 32768) ? 0 : off_s + 16384;
  }

  // ---- epilogue: reduce srun over eg, merge s-halves via LDS, store ----
  srun += __shfl_xor(srun, 16, 64);
  srun += __shfl_xor(srun, 32, 64);
  __syncthreads();  // all K/V reads complete; buffers reusable as merge area
  if (shalf == 1) {
    float* m = (float*)(lds + qg * 4352 + lane * 68);
#pragma unroll
    for (int dc = 0; dc < 4; ++dc)
#pragma unroll
      for (int r = 0; r < 4; ++r) m[dc * 4 + r] = acc[dc][r];
    m[16] = srun;
  }
  __syncthreads();
  if (shalf == 0) {
    const float* m = (const float*)(lds + qg * 4352 + lane * 68);
#pragma unroll
    for (int dc = 0; dc < 4; ++dc)
#pragma unroll
      for (int r = 0; r < 4; ++r) acc[dc][r] += m[dc * 4 + r];
    float inv = 1.f / (srun + m[16]);
    int l = qw0 + qr;
    float* orow = out + (((size_t)b * NL + l) * NH + h) * ND;
#pragma unroll
    for (int dc = 0; dc < 4; ++dc) *(f32x4*)(orow + dc * 16 + eg * 4) = acc[dc] * inv;
  }
}

extern "C" void kernel_launch(void* const* d_in, const int* in_sizes, int n_in,
                              void* d_out, int out_size, void* d_ws, size_t ws_size,
                              hipStream_t stream) {
  const float* q = (const float*)d_in[0];
  const float* k = (const float*)d_in[1];
  const float* v = (const float*)d_in[2];
  // d_in[3] = attn_mask: deterministic triu(k=1) causal mask — applied analytically
  const float* alpha = (const float*)d_in[4];
  float* out = (float*)d_out;
  char* ws = (char*)d_ws;

  __hip_bfloat16* qadj = (__hip_bfloat16*)(ws);                 // 8 MiB [B,H,L,E]
  __hip_bfloat16* kadj = (__hip_bfloat16*)(ws + 8388608);       // 8 MiB [B,H,L,E]
  __hip_bfloat16* vt   = (__hip_bfloat16*)(ws + 16777216);      // 8 MiB [B,H,D,Sperm]
  __hip_bfloat16* qbf  = (__hip_bfloat16*)(ws + 25165824);      // 8 MiB raw bf16 [B,H,L,E]
  __hip_bfloat16* kbf  = (__hip_bfloat16*)(ws + 33554432);      // 8 MiB
  float* pq    = (float*)(ws + 41943040);                       // 2 MiB slab partials
  float* pk    = (float*)(ws + 41943040 + 2097152);             // 2 MiB
  float* qsumT = (float*)(ws + 41943040 + 4194304);             // 8 KiB totals
  float* ksumT = (float*)(ws + 41943040 + 4194304 + 8192);      // 8 KiB

  sums_kernel<<<dim3(1024), 256, 0, stream>>>(q, k, pq, pk, qbf, kbf);
  reduce_kernel<<<dim3(32), 256, 0, stream>>>(pq, pk, qsumT, ksumT);
  prep_kernel<<<dim3(2048), 256, 0, stream>>>(qbf, kbf, v, qsumT, ksumT, alpha, qadj, kadj, vt);
  attn_kernel<<<dim3(32, 32), 512, 0, stream>>>(qadj, kadj, vt, out);
}